// Round 6
// baseline (367.036 us; speedup 1.0000x reference)
//
#include <hip/hip_runtime.h>
#include <hip/hip_bf16.h>

#define GG 64      // B*N graphs
#define LN 2048    // nodes per graph
#define BB 4       // batch
#define NS 16      // sets per batch
#define EE 16384   // edges
#define C_0 64
#define CH 128
#define EPSV 1e-5f
#define VK 16      // variance atomic spread copies
// sliced layout: 8 slices of (32 graphs x 32 ch); slice id = (g>>5)*4 + (c>>5)
// elem addr = sid*SLICE + l*1024 + (g&31)*32 + (c&31)
#define SLICE ((size_t)LN * 1024)

using bf16x8 = __attribute__((ext_vector_type(8))) short;
using f32x4  = __attribute__((ext_vector_type(4))) float;
using u32x4  = __attribute__((ext_vector_type(4))) unsigned int;
typedef unsigned long long ull;

__device__ __forceinline__ float b2f(unsigned short u) {
    union { unsigned int i; float f; } v; v.i = ((unsigned int)u) << 16; return v.f;
}
__device__ __forceinline__ unsigned short f2b(float f) {
    union { float f; unsigned int i; } v; v.f = f;
    unsigned int r = v.i + 0x7fffu + ((v.i >> 16) & 1u);   // RNE
    return (unsigned short)(r >> 16);
}
__device__ __forceinline__ void acc8(float* acc, u32x4 v, float w) {
    acc[0] += w * b2f((unsigned short)(v.x & 0xffffu));
    acc[1] += w * b2f((unsigned short)(v.x >> 16));
    acc[2] += w * b2f((unsigned short)(v.y & 0xffffu));
    acc[3] += w * b2f((unsigned short)(v.y >> 16));
    acc[4] += w * b2f((unsigned short)(v.z & 0xffffu));
    acc[5] += w * b2f((unsigned short)(v.z >> 16));
    acc[6] += w * b2f((unsigned short)(v.w & 0xffffu));
    acc[7] += w * b2f((unsigned short)(v.w >> 16));
}

// ---------- graph preprocessing ----------
__global__ void k_deg(const int* __restrict__ dst, int* __restrict__ cnt) {
    int e = blockIdx.x * blockDim.x + threadIdx.x;
    if (e < EE) atomicAdd(&cnt[dst[e]], 1);
}

__global__ void k_node(const int* __restrict__ cnt, float* __restrict__ dinv,
                       float* __restrict__ selfc) {
    int l = blockIdx.x * blockDim.x + threadIdx.x;
    if (l < LN) {
        float d = (float)cnt[l] + 2.0f;   // improved GCN: A + 2I
        float di = rsqrtf(d);
        dinv[l] = di;
        selfc[l] = 2.0f * di * di;
    }
}

__global__ void k_scan(const int* __restrict__ cnt, int* __restrict__ off) {
    __shared__ int part[256];
    __shared__ int pre[256];
    int t = threadIdx.x;
    int base = t * 8;
    int loc[8];
    int s = 0;
#pragma unroll
    for (int i = 0; i < 8; i++) { loc[i] = cnt[base + i]; s += loc[i]; }
    part[t] = s;
    __syncthreads();
    if (t == 0) {
        int run = 0;
        for (int i = 0; i < 256; i++) { pre[i] = run; run += part[i]; }
        off[LN] = run;
    }
    __syncthreads();
    int run = pre[t];
#pragma unroll
    for (int i = 0; i < 8; i++) { off[base + i] = run; run += loc[i]; }
}

// pack (src, norm) into one 8-byte word per edge
__global__ void k_fill(const int* __restrict__ src, const int* __restrict__ dst,
                       const int* __restrict__ off, int* __restrict__ cur,
                       const float* __restrict__ dinv, ull* __restrict__ epack) {
    int e = blockIdx.x * blockDim.x + threadIdx.x;
    if (e < EE) {
        int s = src[e], d = dst[e];
        int pos = atomicAdd(&cur[d], 1);
        int idx = off[d] + pos;
        union { float f; unsigned u; } w;
        w.f = dinv[s] * dinv[d];
        epack[idx] = (ull)(unsigned)s | ((ull)w.u << 32);
    }
}

// ---------- W -> MFMA-fragment-permuted bf16 ----------
// element (k, c): nf=c>>4, lr=c&15, ks=k>>5, hi=(k>>3)&3, j=k&7
// Wp[(ks*8+nf)*512 + (hi*16+lr)*8 + j]  -> in-kernel frag = 1KB coalesced load
__global__ void k_wprep(const float* __restrict__ W, unsigned short* __restrict__ Wp,
                        int K) {
    int idx = blockIdx.x * 256 + threadIdx.x;
    if (idx < K * CH) {
        int k = idx >> 7, c = idx & (CH - 1);
        int nf = c >> 4, lr = c & 15, ks = k >> 5, hi = (k >> 3) & 3, j = k & 7;
        Wp[(ks * 8 + nf) * 512 + (hi * 16 + lr) * 8 + j] = f2b(W[idx]);
    }
}

// ---------- MFMA GEMM: hw[l,g,co] = sum_k A[l,k] * W[k,co] (bf16, fp32 acc) ----------
// W fragments loaded from global (L2-hot, fragment-permuted) - no W LDS staging.
// FUSE=false: layer 1, A from x fp32 [g][K][LN].
// FUSE=true : A = relu(aPrev * scl + bet)   (aPrev already mean-centered)
template <int K, bool FUSE>
__global__ __launch_bounds__(256) void k_mm(
    const float* __restrict__ X, const unsigned short* __restrict__ Ap,
    const float* __restrict__ scl, const float* __restrict__ bet,
    const unsigned short* __restrict__ Wp, unsigned short* __restrict__ hw)
{
    constexpr int KP = K + 8;                 // LDS k-pad
    __shared__ unsigned short As[64 * 136];   // A tile; reused as C repack buffer
    const int g = blockIdx.y;
    const int l0 = blockIdx.x * 64;
    const int t = threadIdx.x;
    const int wq = t >> 6;
    const int lane = t & 63;

    if (!FUSE) {
        // x fp32 [g][K][LN] -> As[l][k] bf16 (transpose in LDS)
        const int k = t >> 2;
        const int lq = (t & 3) * 16;
        const float* xp = X + ((size_t)g * K + k) * LN + l0 + lq;
#pragma unroll
        for (int i = 0; i < 16; i += 4) {
            float4 v = *(const float4*)&xp[i];
            As[(lq + i + 0) * KP + k] = f2b(v.x);
            As[(lq + i + 1) * KP + k] = f2b(v.y);
            As[(lq + i + 2) * KP + k] = f2b(v.z);
            As[(lq + i + 3) * KP + k] = f2b(v.w);
        }
    } else {
        // fused prev-layer BN+ReLU during staging; Ap is sliced + centered
        const int l = t >> 2;
        const int sc = t & 3;
        const int kq = sc * 32;
        const int sid = (g >> 5) * 4 + sc;
        const unsigned short* ap = Ap + sid * SLICE + (size_t)(l0 + l) * 1024 +
                                   (g & 31) * 32;
        unsigned short* ad = As + l * KP + kq;
#pragma unroll
        for (int i = 0; i < 32; i += 8) {
            union { uint4 v; unsigned short s[8]; } u;
            u.v = *(const uint4*)&ap[i];
            float4 s0 = *(const float4*)&scl[kq + i];
            float4 s1 = *(const float4*)&scl[kq + i + 4];
            float4 c0 = *(const float4*)&bet[kq + i];
            float4 c1 = *(const float4*)&bet[kq + i + 4];
            union { uint4 v; unsigned short s[8]; } o;
            o.s[0] = f2b(fmaxf(b2f(u.s[0]) * s0.x + c0.x, 0.f));
            o.s[1] = f2b(fmaxf(b2f(u.s[1]) * s0.y + c0.y, 0.f));
            o.s[2] = f2b(fmaxf(b2f(u.s[2]) * s0.z + c0.z, 0.f));
            o.s[3] = f2b(fmaxf(b2f(u.s[3]) * s0.w + c0.w, 0.f));
            o.s[4] = f2b(fmaxf(b2f(u.s[4]) * s1.x + c1.x, 0.f));
            o.s[5] = f2b(fmaxf(b2f(u.s[5]) * s1.y + c1.y, 0.f));
            o.s[6] = f2b(fmaxf(b2f(u.s[6]) * s1.z + c1.z, 0.f));
            o.s[7] = f2b(fmaxf(b2f(u.s[7]) * s1.w + c1.w, 0.f));
            *(uint4*)&ad[i] = o.v;
        }
    }
    __syncthreads();

    f32x4 acc[8];
#pragma unroll
    for (int i = 0; i < 8; i++) acc[i] = (f32x4){0.f, 0.f, 0.f, 0.f};
    const int lr = lane & 15;
    const int kof = (lane >> 4) * 8;
#pragma unroll
    for (int ks = 0; ks < K / 32; ks++) {
        bf16x8 aF = *(const bf16x8*)&As[(wq * 16 + lr) * KP + ks * 32 + kof];
#pragma unroll
        for (int nf = 0; nf < 8; nf++) {
            bf16x8 bF = *(const bf16x8*)&Wp[(ks * 8 + nf) * 512 + lane * 8];
            acc[nf] = __builtin_amdgcn_mfma_f32_16x16x32_bf16(aF, bF, acc[nf], 0, 0, 0);
        }
    }
    __syncthreads();
    // repack D (C/D map: col=lane&15, row=(lane>>4)*4+reg) into As (as Cs)
#pragma unroll
    for (int nf = 0; nf < 8; nf++) {
#pragma unroll
        for (int r = 0; r < 4; r++) {
            int row = wq * 16 + (lane >> 4) * 4 + r;
            int col = nf * 16 + lr;
            As[row * 136 + col] = f2b(acc[nf][r]);
        }
    }
    __syncthreads();
    {
        const int l = t >> 2;
        const int sc = t & 3;
        unsigned short* hp = hw + (size_t)((g >> 5) * 4 + sc) * SLICE +
                             (size_t)(l0 + l) * 1024 + (g & 31) * 32;
#pragma unroll
        for (int i = 0; i < 32; i += 8)
            *(uint4*)&hp[i] = *(const uint4*)&As[l * 136 + sc * 32 + i];
    }
}

// ---------- fused gather + center + variance, XCD-pinned slices ----------
// bid = chunk*8 + sid; 4 nodes per chunk; 256 threads = 2 rows x 128 lanes (16B)
// edge metadata: one coalesced 8B load per 64 edges, broadcast via __shfl (readlane)
__global__ __launch_bounds__(256) void k_gnv(
    const unsigned short* __restrict__ hw, unsigned short* __restrict__ a,
    float* __restrict__ varK, const int* __restrict__ off,
    const ull* __restrict__ epack, const float* __restrict__ selfc)
{
    const int bid = blockIdx.x;
    const int sid = bid & 7;
    const int chunk = bid >> 3;          // [0, 512)
    const int l0 = chunk * 4;
    const int t = threadIdx.x;
    const int tr = t >> 7;
    const int ti = t & 127;
    const int lane = t & 63;
    const int go = ti * 8;               // short offset within 1024-short row
    const unsigned short* hws = hw + sid * SLICE;
    unsigned short* aBs = a + sid * SLICE;

    float vacc[8] = {0.f, 0.f, 0.f, 0.f, 0.f, 0.f, 0.f, 0.f};
#pragma unroll
    for (int i = 0; i < 2; i++) {
        const int l = l0 + i * 2 + tr;
        float acc[8];
        u32x4 v0 = *(const u32x4*)&hws[(size_t)l * 1024 + go];
        const int s0 = off[l], s1 = off[l + 1];
        const float sc = selfc[l];
        acc[0] = sc * b2f((unsigned short)(v0.x & 0xffffu));
        acc[1] = sc * b2f((unsigned short)(v0.x >> 16));
        acc[2] = sc * b2f((unsigned short)(v0.y & 0xffffu));
        acc[3] = sc * b2f((unsigned short)(v0.y >> 16));
        acc[4] = sc * b2f((unsigned short)(v0.z & 0xffffu));
        acc[5] = sc * b2f((unsigned short)(v0.z >> 16));
        acc[6] = sc * b2f((unsigned short)(v0.w & 0xffffu));
        acc[7] = sc * b2f((unsigned short)(v0.w >> 16));
        for (int base = s0; base < s1; base += 64) {
            const int cnt = min(64, s1 - base);
            const int li = lane < cnt ? lane : cnt - 1;
            const ull meta = epack[base + li];
            int j = 0;
            for (; j + 2 <= cnt; j += 2) {
                ull m0 = __shfl(meta, j);
                ull m1 = __shfl(meta, j + 1);
                int sA = (int)(unsigned)m0;
                int sB = (int)(unsigned)m1;
                float wA = __uint_as_float((unsigned)(m0 >> 32));
                float wB = __uint_as_float((unsigned)(m1 >> 32));
                u32x4 vA = *(const u32x4*)&hws[(size_t)sA * 1024 + go];
                u32x4 vB = *(const u32x4*)&hws[(size_t)sB * 1024 + go];
                acc8(acc, vA, wA);
                acc8(acc, vB, wB);
            }
            if (j < cnt) {
                ull m0 = __shfl(meta, j);
                int sA = (int)(unsigned)m0;
                float wA = __uint_as_float((unsigned)(m0 >> 32));
                u32x4 vA = *(const u32x4*)&hws[(size_t)sA * 1024 + go];
                acc8(acc, vA, wA);
            }
        }
        // mean over the 16 sets (n-index = lane bits 2..5)
        float m[8];
#pragma unroll
        for (int j2 = 0; j2 < 8; j2++) m[j2] = acc[j2];
#pragma unroll
        for (int mask = 4; mask <= 32; mask <<= 1) {
#pragma unroll
            for (int j2 = 0; j2 < 8; j2++) m[j2] += __shfl_xor(m[j2], mask);
        }
        u32x4 o;
        unsigned short ob[8];
#pragma unroll
        for (int j2 = 0; j2 < 8; j2++) {
            float d = acc[j2] - m[j2] * (1.f / NS);   // centered value
            vacc[j2] += d * d;
            ob[j2] = f2b(d);
        }
        o.x = (unsigned int)ob[0] | ((unsigned int)ob[1] << 16);
        o.y = (unsigned int)ob[2] | ((unsigned int)ob[3] << 16);
        o.z = (unsigned int)ob[4] | ((unsigned int)ob[5] << 16);
        o.w = (unsigned int)ob[6] | ((unsigned int)ob[7] << 16);
        __builtin_nontemporal_store(o, (u32x4*)&aBs[(size_t)l * 1024 + go]);
    }
    // deferred variance butterfly + one atomic burst from lanes 0..3 of each wave
#pragma unroll
    for (int mask = 4; mask <= 32; mask <<= 1) {
#pragma unroll
        for (int j2 = 0; j2 < 8; j2++) vacc[j2] += __shfl_xor(vacc[j2], mask);
    }
    if (lane < 4) {
        float* vp = &varK[(chunk & (VK - 1)) * CH + (sid & 3) * 32 + lane * 8];
#pragma unroll
        for (int j2 = 0; j2 < 8; j2++) atomicAdd(&vp[j2], vacc[j2]);
    }
}

__global__ void k_scale(const float* __restrict__ varK, const float* __restrict__ gam,
                        float* __restrict__ scl) {
    int c = threadIdx.x;
    float v = 0.f;
#pragma unroll
    for (int k = 0; k < VK; k++) v += varK[k * CH + c];
    scl[c] = gam[c] * rsqrtf(v * (1.f / (GG * LN)) + EPSV);
}

// ---------- final epilogue: sliced centered bf16 -> out[g][c][l] fp32 ----------
// bid = chunk*8 + sid; chunk picks 16 nodes
__global__ __launch_bounds__(256) void k_epi_t(
    const unsigned short* __restrict__ a, const float* __restrict__ scl,
    const float* __restrict__ bet, float* __restrict__ out)
{
    __shared__ unsigned short lds[16 * 32 * 40];   // [l][g][c pad40] (16B-aligned rows)
    const int bid = blockIdx.x;
    const int sid = bid & 7;
    const int chunk = bid >> 3;          // [0,128)
    const int l0 = chunk * 16;
    const int t = threadIdx.x;
    const int sg = sid >> 2;
    const int sc = sid & 3;
    const unsigned short* aBs = a + sid * SLICE;
    {
        const int tr = t >> 7;
        const int ti = t & 127;
        const int gl = ti >> 2;
        const int c0 = (ti & 3) * 8;
#pragma unroll
        for (int i = 0; i < 8; i++) {
            const int lloc = i * 2 + tr;
            uint4 v = *(const uint4*)&aBs[(size_t)(l0 + lloc) * 1024 + ti * 8];
            *(uint4*)&lds[(lloc * 32 + gl) * 40 + c0] = v;
        }
    }
    __syncthreads();
#pragma unroll
    for (int it = 0; it < 4; it++) {
        const int p = it * 256 + t;
        const int gl2 = p >> 5;
        const int c2 = p & 31;
        const int cG = sc * 32 + c2;
        const float s = scl[cG], bb = bet[cG];
        float o[16];
#pragma unroll
        for (int l = 0; l < 16; l++)
            o[l] = fmaxf(b2f(lds[(l * 32 + gl2) * 40 + c2]) * s + bb, 0.f);
        float* op = &out[((size_t)(sg * 32 + gl2) * CH + cG) * LN + l0];
#pragma unroll
        for (int l = 0; l < 16; l += 4)
            *(float4*)&op[l] = make_float4(o[l], o[l + 1], o[l + 2], o[l + 3]);
    }
}

extern "C" void kernel_launch(void* const* d_in, const int* in_sizes, int n_in,
                              void* d_out, int out_size, void* d_ws, size_t ws_size,
                              hipStream_t stream) {
    const float* x   = (const float*)d_in[0];
    const int*   ei  = (const int*)d_in[1];
    const float* W1  = (const float*)d_in[2];
    const float* g1  = (const float*)d_in[4];
    const float* be1 = (const float*)d_in[5];
    const float* W2  = (const float*)d_in[6];
    const float* g2  = (const float*)d_in[8];
    const float* be2 = (const float*)d_in[9];
    const float* W3  = (const float*)d_in[10];
    const float* g3  = (const float*)d_in[12];
    const float* be3 = (const float*)d_in[13];
    const int* srcp = ei;
    const int* dstp = ei + EE;

    char* ws = (char*)d_ws;
    size_t pos = 0;
    auto alloc = [&](size_t bytes) -> void* {
        void* p = ws + pos;
        pos = (pos + bytes + 255) & ~(size_t)255;
        return p;
    };
    const size_t big = (size_t)LN * GG * CH * sizeof(unsigned short);  // 33.55 MB
    unsigned short* aB  = (unsigned short*)alloc(big);
    unsigned short* Wt1 = (unsigned short*)alloc(C_0 * CH * 2);
    unsigned short* Wt2 = (unsigned short*)alloc(CH * CH * 2);
    unsigned short* Wt3 = (unsigned short*)alloc(CH * CH * 2);
    int*   cnt   = (int*)alloc(LN * 4);
    int*   offA  = (int*)alloc((LN + 1) * 4);
    int*   cur   = (int*)alloc(LN * 4);
    float* dinv  = (float*)alloc(LN * 4);
    float* selfc = (float*)alloc(LN * 4);
    ull*   epack = (ull*)alloc(EE * 8);
    float* varK  = (float*)alloc(VK * CH * 4);
    float* scl   = (float*)alloc(CH * 4);
    unsigned short* hw = (ws_size >= pos + big) ? (unsigned short*)alloc(big)
                                                : (unsigned short*)d_out;

    // graph preprocessing
    hipMemsetAsync(cnt, 0, LN * 4, stream);
    hipMemsetAsync(cur, 0, LN * 4, stream);
    k_deg<<<EE / 256, 256, 0, stream>>>(dstp, cnt);
    k_node<<<LN / 256, 256, 0, stream>>>(cnt, dinv, selfc);
    k_scan<<<1, 256, 0, stream>>>(cnt, offA);
    k_fill<<<EE / 256, 256, 0, stream>>>(srcp, dstp, offA, cur, dinv, epack);
    k_wprep<<<(C_0 * CH) / 256, 256, 0, stream>>>(W1, Wt1, C_0);
    k_wprep<<<(CH * CH) / 256, 256, 0, stream>>>(W2, Wt2, CH);
    k_wprep<<<(CH * CH) / 256, 256, 0, stream>>>(W3, Wt3, CH);

    dim3 mmG(LN / 64, GG);

    // ---- layer 1 ----
    k_mm<C_0, false><<<mmG, 256, 0, stream>>>(x, nullptr, nullptr, nullptr, Wt1, hw);
    hipMemsetAsync(varK, 0, VK * CH * 4, stream);
    k_gnv<<<512 * 8, 256, 0, stream>>>(hw, aB, varK, offA, epack, selfc);
    k_scale<<<1, CH, 0, stream>>>(varK, g1, scl);

    // ---- layer 2 ----
    k_mm<CH, true><<<mmG, 256, 0, stream>>>(nullptr, aB, scl, be1, Wt2, hw);
    hipMemsetAsync(varK, 0, VK * CH * 4, stream);
    k_gnv<<<512 * 8, 256, 0, stream>>>(hw, aB, varK, offA, epack, selfc);
    k_scale<<<1, CH, 0, stream>>>(varK, g2, scl);

    // ---- layer 3 ----
    k_mm<CH, true><<<mmG, 256, 0, stream>>>(nullptr, aB, scl, be2, Wt3, hw);
    hipMemsetAsync(varK, 0, VK * CH * 4, stream);
    k_gnv<<<512 * 8, 256, 0, stream>>>(hw, aB, varK, offA, epack, selfc);
    k_scale<<<1, CH, 0, stream>>>(varK, g3, scl);

    // ---- output ----
    k_epi_t<<<128 * 8, 256, 0, stream>>>(aB, scl, be3, (float*)d_out);
}

// Round 7
// 244.214 us; speedup vs baseline: 1.5029x; 1.5029x over previous
//
#include <hip/hip_runtime.h>
#include <hip/hip_bf16.h>

#define GG 64      // B*N graphs
#define LN 2048    // nodes per graph
#define BB 4       // batch
#define NS 16      // sets per batch
#define EE 16384   // edges
#define C_0 64
#define CH 128
#define EPSV 1e-5f
#define VK 16      // variance atomic spread copies
#define GNB 8      // nodes per k_gnv chunk
#define ECAP 384   // staged-edge capacity per chunk (mean 64; global fallback beyond)
// sliced layout: 8 slices of (32 graphs x 32 ch); slice id = (g>>5)*4 + (c>>5)
// elem addr = sid*SLICE + l*1024 + (g&31)*32 + (c&31)
#define SLICE ((size_t)LN * 1024)

using bf16x8 = __attribute__((ext_vector_type(8))) short;
using f32x4  = __attribute__((ext_vector_type(4))) float;
using u32x4  = __attribute__((ext_vector_type(4))) unsigned int;
typedef unsigned long long ull;

__device__ __forceinline__ float b2f(unsigned short u) {
    union { unsigned int i; float f; } v; v.i = ((unsigned int)u) << 16; return v.f;
}
__device__ __forceinline__ unsigned short f2b(float f) {
    union { float f; unsigned int i; } v; v.f = f;
    unsigned int r = v.i + 0x7fffu + ((v.i >> 16) & 1u);   // RNE
    return (unsigned short)(r >> 16);
}
__device__ __forceinline__ void acc8(float* acc, u32x4 v, float w) {
    acc[0] += w * b2f((unsigned short)(v.x & 0xffffu));
    acc[1] += w * b2f((unsigned short)(v.x >> 16));
    acc[2] += w * b2f((unsigned short)(v.y & 0xffffu));
    acc[3] += w * b2f((unsigned short)(v.y >> 16));
    acc[4] += w * b2f((unsigned short)(v.z & 0xffffu));
    acc[5] += w * b2f((unsigned short)(v.z >> 16));
    acc[6] += w * b2f((unsigned short)(v.w & 0xffffu));
    acc[7] += w * b2f((unsigned short)(v.w >> 16));
}

// ---------- graph preprocessing ----------
__global__ void k_deg(const int* __restrict__ dst, int* __restrict__ cnt) {
    int e = blockIdx.x * blockDim.x + threadIdx.x;
    if (e < EE) atomicAdd(&cnt[dst[e]], 1);
}

__global__ void k_node(const int* __restrict__ cnt, float* __restrict__ dinv,
                       float* __restrict__ selfc) {
    int l = blockIdx.x * blockDim.x + threadIdx.x;
    if (l < LN) {
        float d = (float)cnt[l] + 2.0f;   // improved GCN: A + 2I
        float di = rsqrtf(d);
        dinv[l] = di;
        selfc[l] = 2.0f * di * di;
    }
}

__global__ void k_scan(const int* __restrict__ cnt, int* __restrict__ off) {
    __shared__ int part[256];
    __shared__ int pre[256];
    int t = threadIdx.x;
    int base = t * 8;
    int loc[8];
    int s = 0;
#pragma unroll
    for (int i = 0; i < 8; i++) { loc[i] = cnt[base + i]; s += loc[i]; }
    part[t] = s;
    __syncthreads();
    if (t == 0) {
        int run = 0;
        for (int i = 0; i < 256; i++) { pre[i] = run; run += part[i]; }
        off[LN] = run;
    }
    __syncthreads();
    int run = pre[t];
#pragma unroll
    for (int i = 0; i < 8; i++) { off[base + i] = run; run += loc[i]; }
}

// pack (src, norm) into one 8-byte word per edge
__global__ void k_fill(const int* __restrict__ src, const int* __restrict__ dst,
                       const int* __restrict__ off, int* __restrict__ cur,
                       const float* __restrict__ dinv, ull* __restrict__ epack) {
    int e = blockIdx.x * blockDim.x + threadIdx.x;
    if (e < EE) {
        int s = src[e], d = dst[e];
        int pos = atomicAdd(&cur[d], 1);
        int idx = off[d] + pos;
        union { float f; unsigned u; } w;
        w.f = dinv[s] * dinv[d];
        epack[idx] = (ull)(unsigned)s | ((ull)w.u << 32);
    }
}

// ---------- W -> MFMA-fragment-permuted bf16 ----------
// element (k, c): nf=c>>4, lr=c&15, ks=k>>5, hi=(k>>3)&3, j=k&7
// Wp[(ks*8+nf)*512 + (hi*16+lr)*8 + j]  -> in-kernel frag = 1KB coalesced wave load
__global__ void k_wprep(const float* __restrict__ W, unsigned short* __restrict__ Wp,
                        int K) {
    int idx = blockIdx.x * 256 + threadIdx.x;
    if (idx < K * CH) {
        int k = idx >> 7, c = idx & (CH - 1);
        int nf = c >> 4, lr = c & 15, ks = k >> 5, hi = (k >> 3) & 3, j = k & 7;
        Wp[(ks * 8 + nf) * 512 + (hi * 16 + lr) * 8 + j] = f2b(W[idx]);
    }
}

// ---------- MFMA GEMM: hw[l,g,co] = sum_k A[l,k] * W[k,co] (bf16, fp32 acc) ----------
// FUSE=false: layer 1, A from x fp32 [g][K][LN] via LDS transpose.
// FUSE=true : A-fragment direct from sliced global aB (16B/lane contiguous),
//             BN+ReLU applied in registers; no A staging, single barrier.
template <int K, bool FUSE>
__global__ __launch_bounds__(256) void k_mm(
    const float* __restrict__ X, const unsigned short* __restrict__ Ap,
    const float* __restrict__ scl, const float* __restrict__ bet,
    const unsigned short* __restrict__ Wp, unsigned short* __restrict__ hw)
{
    constexpr int KP = K + 8;                 // LDS k-pad (!FUSE staging)
    __shared__ unsigned short As[64 * 136];   // A tile (!FUSE) / C repack buffer
    const int g = blockIdx.y;
    const int l0 = blockIdx.x * 64;
    const int t = threadIdx.x;
    const int wq = t >> 6;
    const int lane = t & 63;
    const int lr = lane & 15;
    const int hi = lane >> 4;
    const int kof = hi * 8;

    f32x4 acc[8];
#pragma unroll
    for (int i = 0; i < 8; i++) acc[i] = (f32x4){0.f, 0.f, 0.f, 0.f};

    if (FUSE) {
        const int sg = g >> 5;
        const int gi = g & 31;
        const int row = l0 + wq * 16 + lr;
        bf16x8 aF[K / 32];
#pragma unroll
        for (int ks = 0; ks < K / 32; ks++) {
            const unsigned short* ap = Ap + (size_t)(sg * 4 + ks) * SLICE +
                                       (size_t)row * 1024 + gi * 32 + kof;
            union { uint4 v; unsigned short s[8]; } u;
            u.v = *(const uint4*)ap;
            const int cb = ks * 32 + kof;
            float4 s0 = *(const float4*)&scl[cb];
            float4 s1 = *(const float4*)&scl[cb + 4];
            float4 c0 = *(const float4*)&bet[cb];
            float4 c1 = *(const float4*)&bet[cb + 4];
            union { bf16x8 f; unsigned short s[8]; } o;
            o.s[0] = f2b(fmaxf(b2f(u.s[0]) * s0.x + c0.x, 0.f));
            o.s[1] = f2b(fmaxf(b2f(u.s[1]) * s0.y + c0.y, 0.f));
            o.s[2] = f2b(fmaxf(b2f(u.s[2]) * s0.z + c0.z, 0.f));
            o.s[3] = f2b(fmaxf(b2f(u.s[3]) * s0.w + c0.w, 0.f));
            o.s[4] = f2b(fmaxf(b2f(u.s[4]) * s1.x + c1.x, 0.f));
            o.s[5] = f2b(fmaxf(b2f(u.s[5]) * s1.y + c1.y, 0.f));
            o.s[6] = f2b(fmaxf(b2f(u.s[6]) * s1.z + c1.z, 0.f));
            o.s[7] = f2b(fmaxf(b2f(u.s[7]) * s1.w + c1.w, 0.f));
            aF[ks] = o.f;
        }
#pragma unroll
        for (int ks = 0; ks < K / 32; ks++) {
#pragma unroll
            for (int nf = 0; nf < 8; nf++) {
                bf16x8 bF = *(const bf16x8*)&Wp[(ks * 8 + nf) * 512 + lane * 8];
                acc[nf] = __builtin_amdgcn_mfma_f32_16x16x32_bf16(aF[ks], bF,
                                                                  acc[nf], 0, 0, 0);
            }
        }
    } else {
        // x fp32 [g][K][LN] -> As[l][k] bf16 (transpose in LDS)
        const int k = t >> 2;
        const int lq = (t & 3) * 16;
        const float* xp = X + ((size_t)g * K + k) * LN + l0 + lq;
#pragma unroll
        for (int i = 0; i < 16; i += 4) {
            float4 v = *(const float4*)&xp[i];
            As[(lq + i + 0) * KP + k] = f2b(v.x);
            As[(lq + i + 1) * KP + k] = f2b(v.y);
            As[(lq + i + 2) * KP + k] = f2b(v.z);
            As[(lq + i + 3) * KP + k] = f2b(v.w);
        }
        __syncthreads();
#pragma unroll
        for (int ks = 0; ks < K / 32; ks++) {
            bf16x8 aF = *(const bf16x8*)&As[(wq * 16 + lr) * KP + ks * 32 + kof];
#pragma unroll
            for (int nf = 0; nf < 8; nf++) {
                bf16x8 bF = *(const bf16x8*)&Wp[(ks * 8 + nf) * 512 + lane * 8];
                acc[nf] = __builtin_amdgcn_mfma_f32_16x16x32_bf16(aF, bF,
                                                                  acc[nf], 0, 0, 0);
            }
        }
        __syncthreads();   // As about to be overwritten by C repack (overlapping strides)
    }
    // repack D (C/D map: col=lane&15, row=(lane>>4)*4+reg) into As
#pragma unroll
    for (int nf = 0; nf < 8; nf++) {
#pragma unroll
        for (int r = 0; r < 4; r++) {
            int row = wq * 16 + (lane >> 4) * 4 + r;
            int col = nf * 16 + lr;
            As[row * 136 + col] = f2b(acc[nf][r]);
        }
    }
    __syncthreads();
    {
        const int l = t >> 2;
        const int sc = t & 3;
        unsigned short* hp = hw + (size_t)((g >> 5) * 4 + sc) * SLICE +
                             (size_t)(l0 + l) * 1024 + (g & 31) * 32;
#pragma unroll
        for (int i = 0; i < 32; i += 8)
            *(uint4*)&hp[i] = *(const uint4*)&As[l * 136 + sc * 32 + i];
    }
}

// ---------- fused gather + center + variance, XCD-pinned slices ----------
// bid = chunk*8 + sid; GNB nodes per chunk; 256 threads = 2 rows x 128 lanes (16B)
// edge metadata staged in LDS up front -> gather addresses have no global dependency
__global__ __launch_bounds__(256) void k_gnv(
    const unsigned short* __restrict__ hw, unsigned short* __restrict__ a,
    float* __restrict__ varK, const int* __restrict__ off,
    const ull* __restrict__ epack, const float* __restrict__ selfc)
{
    __shared__ ull emeta[ECAP];
    __shared__ int soff[GNB + 1];
    __shared__ float sselfc[GNB];
    __shared__ float vred[4][32];
    const int bid = blockIdx.x;
    const int sid = bid & 7;
    const int chunk = bid >> 3;          // [0, LN/GNB)
    const int l0 = chunk * GNB;
    const int t = threadIdx.x;
    const int tr = t >> 7;
    const int ti = t & 127;
    const int lane = t & 63;
    const int wq = t >> 6;
    const int go = ti * 8;               // short offset within 1024-short row
    const unsigned short* hws = hw + sid * SLICE;
    unsigned short* aBs = a + sid * SLICE;

    // prefetch self rows (independent of LDS)
    u32x4 v0s[GNB / 2];
#pragma unroll
    for (int ii = 0; ii < GNB / 2; ii++)
        v0s[ii] = *(const u32x4*)&hws[(size_t)(l0 + ii * 2 + tr) * 1024 + go];

    // stage metadata
    const int e0 = off[l0];
    const int eTot = off[l0 + GNB] - e0;
    if (t <= GNB) soff[t] = off[l0 + t];
    if (t >= 32 && t < 32 + GNB) sselfc[t - 32] = selfc[l0 + t - 32];
    const int estg = eTot < ECAP ? eTot : ECAP;
    for (int i = t; i < estg; i += 256) emeta[i] = epack[e0 + i];
    __syncthreads();

    float vacc[8] = {0.f, 0.f, 0.f, 0.f, 0.f, 0.f, 0.f, 0.f};

    auto gather = [&](const ull* __restrict__ mp) {
#pragma unroll
        for (int ii = 0; ii < GNB / 2; ii++) {
            const int ln = ii * 2 + tr;
            const int l = l0 + ln;
            const int s0 = soff[ln] - e0;
            const int s1 = soff[ln + 1] - e0;
            const float sc = sselfc[ln];
            float acc[8];
            {
                u32x4 v0 = v0s[ii];
                acc[0] = sc * b2f((unsigned short)(v0.x & 0xffffu));
                acc[1] = sc * b2f((unsigned short)(v0.x >> 16));
                acc[2] = sc * b2f((unsigned short)(v0.y & 0xffffu));
                acc[3] = sc * b2f((unsigned short)(v0.y >> 16));
                acc[4] = sc * b2f((unsigned short)(v0.z & 0xffffu));
                acc[5] = sc * b2f((unsigned short)(v0.z >> 16));
                acc[6] = sc * b2f((unsigned short)(v0.w & 0xffffu));
                acc[7] = sc * b2f((unsigned short)(v0.w >> 16));
            }
            int e = s0;
            for (; e + 4 <= s1; e += 4) {
                ull m0 = mp[e], m1 = mp[e + 1], m2 = mp[e + 2], m3 = mp[e + 3];
                u32x4 vA = *(const u32x4*)&hws[(size_t)(unsigned)m0 * 1024 + go];
                u32x4 vB = *(const u32x4*)&hws[(size_t)(unsigned)m1 * 1024 + go];
                u32x4 vC = *(const u32x4*)&hws[(size_t)(unsigned)m2 * 1024 + go];
                u32x4 vD = *(const u32x4*)&hws[(size_t)(unsigned)m3 * 1024 + go];
                acc8(acc, vA, __uint_as_float((unsigned)(m0 >> 32)));
                acc8(acc, vB, __uint_as_float((unsigned)(m1 >> 32)));
                acc8(acc, vC, __uint_as_float((unsigned)(m2 >> 32)));
                acc8(acc, vD, __uint_as_float((unsigned)(m3 >> 32)));
            }
            for (; e < s1; e++) {
                ull m0 = mp[e];
                u32x4 vA = *(const u32x4*)&hws[(size_t)(unsigned)m0 * 1024 + go];
                acc8(acc, vA, __uint_as_float((unsigned)(m0 >> 32)));
            }
            // mean over the 16 sets (n-index = lane bits 2..5)
            float m[8];
#pragma unroll
            for (int j = 0; j < 8; j++) m[j] = acc[j];
#pragma unroll
            for (int mask = 4; mask <= 32; mask <<= 1) {
#pragma unroll
                for (int j = 0; j < 8; j++) m[j] += __shfl_xor(m[j], mask);
            }
            u32x4 o;
            unsigned short ob[8];
#pragma unroll
            for (int j = 0; j < 8; j++) {
                float d = acc[j] - m[j] * (1.f / NS);   // centered value
                vacc[j] += d * d;
                ob[j] = f2b(d);
            }
            o.x = (unsigned int)ob[0] | ((unsigned int)ob[1] << 16);
            o.y = (unsigned int)ob[2] | ((unsigned int)ob[3] << 16);
            o.z = (unsigned int)ob[4] | ((unsigned int)ob[5] << 16);
            o.w = (unsigned int)ob[6] | ((unsigned int)ob[7] << 16);
            __builtin_nontemporal_store(o, (u32x4*)&aBs[(size_t)l * 1024 + go]);
        }
    };
    if (eTot <= ECAP) gather(emeta);
    else gather(epack + e0);           // pathological-degree fallback (never in practice)

    // variance: butterfly within wave, cross-wave LDS reduce, 32 atomics/block
#pragma unroll
    for (int mask = 4; mask <= 32; mask <<= 1) {
#pragma unroll
        for (int j = 0; j < 8; j++) vacc[j] += __shfl_xor(vacc[j], mask);
    }
    if (lane < 4) {
#pragma unroll
        for (int j = 0; j < 8; j++) vred[wq][lane * 8 + j] = vacc[j];
    }
    __syncthreads();
    if (t < 32) {
        float s = vred[0][t] + vred[1][t] + vred[2][t] + vred[3][t];
        atomicAdd(&varK[(chunk & (VK - 1)) * CH + (sid & 3) * 32 + t], s);
    }
}

__global__ void k_scale(const float* __restrict__ varK, const float* __restrict__ gam,
                        float* __restrict__ scl) {
    int c = threadIdx.x;
    float v = 0.f;
#pragma unroll
    for (int k = 0; k < VK; k++) v += varK[k * CH + c];
    scl[c] = gam[c] * rsqrtf(v * (1.f / (GG * LN)) + EPSV);
}

// ---------- final epilogue: sliced centered bf16 -> out[g][c][l] fp32 ----------
// bid = chunk*8 + sid; chunk picks 16 nodes
__global__ __launch_bounds__(256) void k_epi_t(
    const unsigned short* __restrict__ a, const float* __restrict__ scl,
    const float* __restrict__ bet, float* __restrict__ out)
{
    __shared__ unsigned short lds[16 * 32 * 40];   // [l][g][c pad40] (16B-aligned rows)
    const int bid = blockIdx.x;
    const int sid = bid & 7;
    const int chunk = bid >> 3;          // [0,128)
    const int l0 = chunk * 16;
    const int t = threadIdx.x;
    const int sg = sid >> 2;
    const int sc = sid & 3;
    const unsigned short* aBs = a + sid * SLICE;
    {
        const int tr = t >> 7;
        const int ti = t & 127;
        const int gl = ti >> 2;
        const int c0 = (ti & 3) * 8;
#pragma unroll
        for (int i = 0; i < 8; i++) {
            const int lloc = i * 2 + tr;
            uint4 v = *(const uint4*)&aBs[(size_t)(l0 + lloc) * 1024 + ti * 8];
            *(uint4*)&lds[(lloc * 32 + gl) * 40 + c0] = v;
        }
    }
    __syncthreads();
#pragma unroll
    for (int it = 0; it < 4; it++) {
        const int p = it * 256 + t;
        const int gl2 = p >> 5;
        const int c2 = p & 31;
        const int cG = sc * 32 + c2;
        const float s = scl[cG], bb = bet[cG];
        float o[16];
#pragma unroll
        for (int l = 0; l < 16; l++)
            o[l] = fmaxf(b2f(lds[(l * 32 + gl2) * 40 + c2]) * s + bb, 0.f);
        float* op = &out[((size_t)(sg * 32 + gl2) * CH + cG) * LN + l0];
#pragma unroll
        for (int l = 0; l < 16; l += 4)
            *(float4*)&op[l] = make_float4(o[l], o[l + 1], o[l + 2], o[l + 3]);
    }
}

extern "C" void kernel_launch(void* const* d_in, const int* in_sizes, int n_in,
                              void* d_out, int out_size, void* d_ws, size_t ws_size,
                              hipStream_t stream) {
    const float* x   = (const float*)d_in[0];
    const int*   ei  = (const int*)d_in[1];
    const float* W1  = (const float*)d_in[2];
    const float* g1  = (const float*)d_in[4];
    const float* be1 = (const float*)d_in[5];
    const float* W2  = (const float*)d_in[6];
    const float* g2  = (const float*)d_in[8];
    const float* be2 = (const float*)d_in[9];
    const float* W3  = (const float*)d_in[10];
    const float* g3  = (const float*)d_in[12];
    const float* be3 = (const float*)d_in[13];
    const int* srcp = ei;
    const int* dstp = ei + EE;

    char* ws = (char*)d_ws;
    size_t pos = 0;
    auto alloc = [&](size_t bytes) -> void* {
        void* p = ws + pos;
        pos = (pos + bytes + 255) & ~(size_t)255;
        return p;
    };
    const size_t big = (size_t)LN * GG * CH * sizeof(unsigned short);  // 33.55 MB
    unsigned short* aB  = (unsigned short*)alloc(big);
    unsigned short* Wt1 = (unsigned short*)alloc(C_0 * CH * 2);
    unsigned short* Wt2 = (unsigned short*)alloc(CH * CH * 2);
    unsigned short* Wt3 = (unsigned short*)alloc(CH * CH * 2);
    int*   cnt   = (int*)alloc(LN * 4);
    int*   offA  = (int*)alloc((LN + 1) * 4);
    int*   cur   = (int*)alloc(LN * 4);
    float* dinv  = (float*)alloc(LN * 4);
    float* selfc = (float*)alloc(LN * 4);
    ull*   epack = (ull*)alloc(EE * 8);
    float* varK  = (float*)alloc(VK * CH * 4);
    float* scl   = (float*)alloc(CH * 4);
    unsigned short* hw = (ws_size >= pos + big) ? (unsigned short*)alloc(big)
                                                : (unsigned short*)d_out;

    // graph preprocessing
    hipMemsetAsync(cnt, 0, LN * 4, stream);
    hipMemsetAsync(cur, 0, LN * 4, stream);
    k_deg<<<EE / 256, 256, 0, stream>>>(dstp, cnt);
    k_node<<<LN / 256, 256, 0, stream>>>(cnt, dinv, selfc);
    k_scan<<<1, 256, 0, stream>>>(cnt, offA);
    k_fill<<<EE / 256, 256, 0, stream>>>(srcp, dstp, offA, cur, dinv, epack);
    k_wprep<<<(C_0 * CH) / 256, 256, 0, stream>>>(W1, Wt1, C_0);
    k_wprep<<<(CH * CH) / 256, 256, 0, stream>>>(W2, Wt2, CH);
    k_wprep<<<(CH * CH) / 256, 256, 0, stream>>>(W3, Wt3, CH);

    dim3 mmG(LN / 64, GG);
    const int gnvG = (LN / GNB) * 8;

    // ---- layer 1 ----
    k_mm<C_0, false><<<mmG, 256, 0, stream>>>(x, nullptr, nullptr, nullptr, Wt1, hw);
    hipMemsetAsync(varK, 0, VK * CH * 4, stream);
    k_gnv<<<gnvG, 256, 0, stream>>>(hw, aB, varK, offA, epack, selfc);
    k_scale<<<1, CH, 0, stream>>>(varK, g1, scl);

    // ---- layer 2 ----
    k_mm<CH, true><<<mmG, 256, 0, stream>>>(nullptr, aB, scl, be1, Wt2, hw);
    hipMemsetAsync(varK, 0, VK * CH * 4, stream);
    k_gnv<<<gnvG, 256, 0, stream>>>(hw, aB, varK, offA, epack, selfc);
    k_scale<<<1, CH, 0, stream>>>(varK, g2, scl);

    // ---- layer 3 ----
    k_mm<CH, true><<<mmG, 256, 0, stream>>>(nullptr, aB, scl, be2, Wt3, hw);
    hipMemsetAsync(varK, 0, VK * CH * 4, stream);
    k_gnv<<<gnvG, 256, 0, stream>>>(hw, aB, varK, offA, epack, selfc);
    k_scale<<<1, CH, 0, stream>>>(varK, g3, scl);

    // ---- output ----
    k_epi_t<<<128 * 8, 256, 0, stream>>>(aB, scl, be3, (float*)d_out);
}